// Round 2
// baseline (3258.889 us; speedup 1.0000x reference)
//
#include <hip/hip_runtime.h>
#include <math.h>

#define ENC_K 49152
#define KSEG 8
#define KLEN (ENC_K / KSEG)   // 6144

// ---------------- alpha_bar per batch ----------------
__global__ void k_alpha(const int* __restrict__ t, float* __restrict__ sab, float* __restrict__ snab) {
    int b = threadIdx.x;
    if (b < 64) {
        int tb = t[b];
        const float step = (0.02f - 1e-4f) / 999.0f;
        float ab = 1.0f;
        for (int i = 0; i <= tb; ++i) {
            float beta = 1e-4f + step * (float)i;
            ab *= (1.0f - beta);
        }
        sab[b] = sqrtf(ab);
        snab[b] = sqrtf(1.0f - ab);
    }
}

// ---------------- encoder GEMM: x0 = cond @ W^T (K-split partials) ----------------
__global__ void k_enc_gemm(const float* __restrict__ cond, const float* __restrict__ w,
                           float* __restrict__ partial) {
    __shared__ float As[16][65];
    __shared__ float Ws[16][65];
    int tid = threadIdx.x;
    int j = tid & 15, i = tid >> 4;
    int d0 = blockIdx.x * 16, b0 = blockIdx.y * 16;
    int k0 = blockIdx.z * KLEN;
    float acc = 0.f;
    for (int kk = 0; kk < KLEN; kk += 64) {
        for (int idx = tid; idx < 1024; idx += 256) {
            int r = idx >> 6, c = idx & 63;
            As[r][c] = cond[(size_t)(b0 + r) * ENC_K + k0 + kk + c];
            Ws[r][c] = w[(size_t)(d0 + r) * ENC_K + k0 + kk + c];
        }
        __syncthreads();
#pragma unroll
        for (int k = 0; k < 64; ++k)
            acc += As[i][k] * Ws[j][k];
        __syncthreads();
    }
    partial[((size_t)blockIdx.z * 64 + b0 + i) * 128 + d0 + j] = acc;
}

__global__ void k_enc_reduce(const float* __restrict__ partial, const float* __restrict__ bias,
                             float* __restrict__ x0) {
    int idx = blockIdx.x * 256 + threadIdx.x;  // 8192 total
    float s = bias[idx & 127];
    for (int ks = 0; ks < KSEG; ++ks) s += partial[(size_t)ks * 8192 + idx];
    x0[idx] = s;
}

// ---------------- transformer encoder (2 layers, seq_len 1) ----------------
__device__ float block_ln(float y, float* rbuf, int d, float g, float bb) {
    rbuf[d] = y;
    __syncthreads();
    for (int s = 64; s > 0; s >>= 1) { if (d < s) rbuf[d] += rbuf[d + s]; __syncthreads(); }
    float mean = rbuf[0] / 128.f;
    __syncthreads();
    float c = y - mean;
    rbuf[d] = c * c;
    __syncthreads();
    for (int s = 64; s > 0; s >>= 1) { if (d < s) rbuf[d] += rbuf[d + s]; __syncthreads(); }
    float var = rbuf[0] / 128.f;
    __syncthreads();
    return c * rsqrtf(var + 1e-5f) * g + bb;
}

__global__ void k_tf(const float* __restrict__ x0, float* __restrict__ xe,
                     const float* __restrict__ in_w, const float* __restrict__ in_b,
                     const float* __restrict__ out_w, const float* __restrict__ out_b,
                     const float* __restrict__ ff1_w, const float* __restrict__ ff1_b,
                     const float* __restrict__ ff2_w, const float* __restrict__ ff2_b,
                     const float* __restrict__ ln1_g, const float* __restrict__ ln1_b,
                     const float* __restrict__ ln2_g, const float* __restrict__ ln2_b) {
    __shared__ float xs[128], vs[128], f1[2048], rbuf[128];
    int b = blockIdx.x, d = threadIdx.x;
    xs[d] = x0[b * 128 + d];
    __syncthreads();
    for (int L = 0; L < 2; ++L) {
        const float* iw = in_w + (size_t)L * 384 * 128 + 256 * 128;
        const float* ibv = in_b + L * 384 + 256;
        float s = ibv[d];
        for (int k = 0; k < 128; ++k) s += xs[k] * iw[d * 128 + k];
        vs[d] = s;
        __syncthreads();
        float a = out_b[L * 128 + d];
        const float* ow = out_w + (size_t)L * 128 * 128 + d * 128;
        for (int k = 0; k < 128; ++k) a += vs[k] * ow[k];
        float y = xs[d] + a;
        y = block_ln(y, rbuf, d, ln1_g[L * 128 + d], ln1_b[L * 128 + d]);
        xs[d] = y;
        __syncthreads();
        for (int j = d; j < 2048; j += 128) {
            float f = ff1_b[L * 2048 + j];
            const float* w1 = ff1_w + (size_t)L * 2048 * 128 + (size_t)j * 128;
            for (int k = 0; k < 128; ++k) f += xs[k] * w1[k];
            f1[j] = fmaxf(f, 0.f);
        }
        __syncthreads();
        float f2 = ff2_b[L * 128 + d];
        const float* w2 = ff2_w + (size_t)L * 128 * 2048 + (size_t)d * 2048;
        for (int k = 0; k < 2048; ++k) f2 += f1[k] * w2[k];
        y = xs[d] + f2;
        y = block_ln(y, rbuf, d, ln2_g[L * 128 + d], ln2_b[L * 128 + d]);
        xs[d] = y;
        __syncthreads();
    }
    xe[b * 128 + d] = xs[d];
}

// ---------------- mid projection ----------------
__global__ void k_mid(const float* __restrict__ xe, const float* __restrict__ mid_w,
                      const float* __restrict__ mid_b, float* __restrict__ mid) {
    int b = blockIdx.x, c = threadIdx.x;  // 64 threads
    float s = mid_b[c];
    const float* xr = xe + b * 128;
    const float* wr = mid_w + c * 128;
    for (int k = 0; k < 128; ++k) s += xr[k] * wr[k];
    mid[b * 64 + c] = s;
}

// ---------------- direct 3x3 SAME conv, 16x16 spatial tiles, batch-chunked ----------------
// MIN: 0 = read `in` (chunk-local); 1 = fused q_sample from tgt/noise (global batch idx)
// MOUT: 0 = bias; 1 = relu; 2 = relu+mid; 3 = bias + fused MSE partial (COUT==3)
template <int CIN, int COUT, int CC, int COT, int MIN, int MOUT>
__global__ void k_conv(const float* __restrict__ in, const float* __restrict__ tgt,
                       const float* __restrict__ noise, const float* __restrict__ sab,
                       const float* __restrict__ snab, const float* __restrict__ wgt,
                       const float* __restrict__ bias, const float* __restrict__ mid,
                       float* __restrict__ out, float* __restrict__ partial, int b0) {
    __shared__ float it[CC][18][18];
    __shared__ float wt[COT][CC][9];
    __shared__ float rs[256];
    int tid = threadIdx.x;
    int tx = tid & 15, ty = tid >> 4;
    int bx = blockIdx.x, by = blockIdx.y;
    const int GROUPS = COUT / COT;
    int bl = blockIdx.z / GROUPS;       // chunk-local batch index (for ws buffers)
    int g = blockIdx.z % GROUPS;
    int bg = b0 + bl;                   // global batch index (for tgt/noise/sab/mid/mse)
    int co0 = g * COT;

    float acc[COT];
#pragma unroll
    for (int c = 0; c < COT; ++c) acc[c] = 0.f;
    float za = 0.f, zb = 0.f;
    if (MIN == 1) { za = sab[bg]; zb = snab[bg]; }

    for (int c0 = 0; c0 < CIN; c0 += CC) {
        for (int idx = tid; idx < CC * 324; idx += 256) {
            int c = idx / 324, rem = idx % 324;
            int yy = rem / 18, xx = rem % 18;
            int gy = by * 16 + yy - 1, gx = bx * 16 + xx - 1;
            float v = 0.f;
            if (gy >= 0 && gy < 128 && gx >= 0 && gx < 128) {
                if (MIN == 1) {
                    size_t off = (((size_t)bg * CIN + c0 + c) * 128 + gy) * 128 + gx;
                    v = za * tgt[off] + zb * noise[off];
                } else {
                    size_t off = (((size_t)bl * CIN + c0 + c) * 128 + gy) * 128 + gx;
                    v = in[off];
                }
            }
            it[c][yy][xx] = v;
        }
        for (int idx = tid; idx < COT * CC * 9; idx += 256) {
            int co = idx / (CC * 9), rem = idx % (CC * 9);
            int c = rem / 9, k = rem % 9;
            wt[co][c][k] = wgt[((size_t)(co0 + co) * CIN + c0 + c) * 9 + k];
        }
        __syncthreads();
#pragma unroll
        for (int c = 0; c < CC; ++c) {
#pragma unroll
            for (int k = 0; k < 9; ++k) {
                int ky = k / 3, kx = k % 3;
                float iv = it[c][ty + ky][tx + kx];
#pragma unroll
                for (int co = 0; co < COT; ++co) acc[co] += iv * wt[co][c][k];
            }
        }
        __syncthreads();
    }

    int gy = by * 16 + ty, gx = bx * 16 + tx;
    if (MOUT == 3) {
        float ss = 0.f;
#pragma unroll
        for (int co = 0; co < COT; ++co) {
            float v = acc[co] + bias[co0 + co];
            size_t off = (((size_t)bg * COUT + co) * 128 + gy) * 128 + gx;
            float diff = v - noise[off];
            ss += diff * diff;
        }
        rs[tid] = ss;
        __syncthreads();
        for (int s = 128; s > 0; s >>= 1) { if (tid < s) rs[tid] += rs[tid + s]; __syncthreads(); }
        if (tid == 0) partial[(((size_t)bg * GROUPS + g) * 8 + by) * 8 + bx] = rs[0];
    } else {
#pragma unroll
        for (int co = 0; co < COT; ++co) {
            float v = acc[co] + bias[co0 + co];
            if (MOUT >= 1) v = fmaxf(v, 0.f);
            if (MOUT == 2) v += mid[bg * 64 + co0 + co];
            out[(((size_t)bl * COUT + co0 + co) * 128 + gy) * 128 + gx] = v;
        }
    }
}

// ---------------- final MSE reduction ----------------
__global__ void k_final(const float* __restrict__ partial, float* __restrict__ out) {
    __shared__ float rs[256];
    int tid = threadIdx.x;
    float s = 0.f;
    for (int i = tid; i < 4096; i += 256) s += partial[i];
    rs[tid] = s;
    __syncthreads();
    for (int st = 128; st > 0; st >>= 1) { if (tid < st) rs[tid] += rs[tid + st]; __syncthreads(); }
    if (tid == 0) out[0] = rs[0] / 3145728.0f;
}

extern "C" void kernel_launch(void* const* d_in, const int* in_sizes, int n_in,
                              void* d_out, int out_size, void* d_ws, size_t ws_size,
                              hipStream_t stream) {
    const float* cond   = (const float*)d_in[0];
    const float* tgt    = (const float*)d_in[1];
    const float* noise  = (const float*)d_in[2];
    const int*   t      = (const int*)d_in[3];
    const float* enc_w  = (const float*)d_in[4];
    const float* enc_b  = (const float*)d_in[5];
    const float* in_w   = (const float*)d_in[6];
    const float* in_b   = (const float*)d_in[7];
    const float* out_w  = (const float*)d_in[8];
    const float* out_b  = (const float*)d_in[9];
    const float* ff1_w  = (const float*)d_in[10];
    const float* ff1_b  = (const float*)d_in[11];
    const float* ff2_w  = (const float*)d_in[12];
    const float* ff2_b  = (const float*)d_in[13];
    const float* ln1_g  = (const float*)d_in[14];
    const float* ln1_b  = (const float*)d_in[15];
    const float* ln2_g  = (const float*)d_in[16];
    const float* ln2_b  = (const float*)d_in[17];
    const float* d1_w   = (const float*)d_in[18];
    const float* d1_b   = (const float*)d_in[19];
    const float* d2_w   = (const float*)d_in[20];
    const float* d2_b   = (const float*)d_in[21];
    const float* mid_w  = (const float*)d_in[22];
    const float* mid_b  = (const float*)d_in[23];
    const float* u1_w   = (const float*)d_in[24];
    const float* u1_b   = (const float*)d_in[25];
    const float* u2_w   = (const float*)d_in[26];
    const float* u2_b   = (const float*)d_in[27];

    float* ws = (float*)d_ws;
    // control region: 131072 floats
    float* sab     = ws;                    // 64
    float* snab    = ws + 64;               // 64
    float* x0      = ws + 128;              // 8192
    float* xe      = ws + 8320;             // 8192
    float* mid     = ws + 16512;            // 4096
    float* encpart = ws + 20608;            // 65536
    float* msepart = ws + 86144;            // 4096

    // ws-adaptive batch chunk: NB images of h1(32ch)+h2(64ch)+h3(32ch) = NB*2097152 floats
    const size_t SMALL = 131072;
    size_t avail = (ws_size / 4 > SMALL) ? (ws_size / 4 - SMALL) : 0;
    int NB = 1;
    const int cands[7] = {64, 32, 16, 8, 4, 2, 1};
    for (int ci = 0; ci < 7; ++ci) {
        if ((size_t)cands[ci] * 2097152ull <= avail) { NB = cands[ci]; break; }
    }
    float* h1 = ws + SMALL;                                  // NB*32*128*128
    float* h2 = h1 + (size_t)NB * 524288ull;                 // NB*64*128*128
    float* h3 = h2 + (size_t)NB * 1048576ull;                // NB*32*128*128

    k_alpha<<<1, 64, 0, stream>>>(t, sab, snab);
    k_enc_gemm<<<dim3(8, 4, KSEG), 256, 0, stream>>>(cond, enc_w, encpart);
    k_enc_reduce<<<32, 256, 0, stream>>>(encpart, enc_b, x0);
    k_tf<<<64, 128, 0, stream>>>(x0, xe, in_w, in_b, out_w, out_b,
                                 ff1_w, ff1_b, ff2_w, ff2_b,
                                 ln1_g, ln1_b, ln2_g, ln2_b);
    k_mid<<<64, 64, 0, stream>>>(xe, mid_w, mid_b, mid);

    for (int cb = 0; cb < 64; cb += NB) {
        // conv1: 3->32, fused q_sample, relu
        k_conv<3, 32, 3, 16, 1, 1><<<dim3(8, 8, NB * 2), 256, 0, stream>>>(
            nullptr, tgt, noise, sab, snab, d1_w, d1_b, nullptr, h1, nullptr, cb);
        // conv2: 32->64, relu + mid add
        k_conv<32, 64, 8, 16, 0, 2><<<dim3(8, 8, NB * 4), 256, 0, stream>>>(
            h1, nullptr, nullptr, nullptr, nullptr, d2_w, d2_b, mid, h2, nullptr, cb);
        // u1: 64->32, relu
        k_conv<64, 32, 8, 16, 0, 1><<<dim3(8, 8, NB * 2), 256, 0, stream>>>(
            h2, nullptr, nullptr, nullptr, nullptr, u1_w, u1_b, nullptr, h3, nullptr, cb);
        // u2: 32->3, fused MSE partials
        k_conv<32, 3, 8, 3, 0, 3><<<dim3(8, 8, NB * 1), 256, 0, stream>>>(
            h3, nullptr, noise, nullptr, nullptr, u2_w, u2_b, nullptr, nullptr, msepart, cb);
    }

    k_final<<<1, 256, 0, stream>>>(msepart, (float*)d_out);
}